// Round 6
// baseline (1194.099 us; speedup 1.0000x reference)
//
#include <hip/hip_runtime.h>
#include <math.h>

#define Nn    100000
#define Ee    3200000
#define NNZn  6400000
#define NF    (Nn * 16)     // floats per node-feature buffer
#define K     256           // coarse row buckets (512B pm write runs)
#define RPB   391           // rows per bucket = ceil(Nn/K)
#define CHUNK 16384         // items per binning block

// ---------------------------------------------------------------------------
// Coarse count: per-block LDS histogram of key/RPB, one global atomic/bucket.
// int4-vectorized key loads.
// ---------------------------------------------------------------------------
__global__ __launch_bounds__(256) void count_kernel(
    const int* __restrict__ keys, int n, int* __restrict__ tot) {
  __shared__ int h[K];
  int t = threadIdx.x;
  if (t < K) h[t] = 0;
  __syncthreads();
  int base = blockIdx.x * CHUNK;
  int end = min(base + CHUNK, n);
  for (int i = base + t * 4; i < end; i += 1024) {
    int4 k4 = *(const int4*)(keys + i);
    atomicAdd(&h[k4.x / RPB], 1);
    atomicAdd(&h[k4.y / RPB], 1);
    atomicAdd(&h[k4.z / RPB], 1);
    atomicAdd(&h[k4.w / RPB], 1);
  }
  __syncthreads();
  if (t < K && h[t]) atomicAdd(&tot[t], h[t]);
}

// ---------------------------------------------------------------------------
// Exclusive scan of K bucket totals -> bucket_start + cursor. 2 blocks x K.
// ---------------------------------------------------------------------------
__global__ __launch_bounds__(K) void scan_kernel(
    const int* __restrict__ tot_e, const int* __restrict__ tot_p,
    int* __restrict__ bs_e, int* __restrict__ cur_e,
    int* __restrict__ bs_p, int* __restrict__ cur_p) {
  const int* tot = (blockIdx.x == 0) ? tot_e : tot_p;
  int* bs  = (blockIdx.x == 0) ? bs_e  : bs_p;
  int* cur = (blockIdx.x == 0) ? cur_e : cur_p;
  __shared__ int s[K];
  int t = threadIdx.x;
  s[t] = tot[t];
  __syncthreads();
  for (int off = 1; off < K; off <<= 1) {
    int v = (t >= off) ? s[t - off] : 0;
    __syncthreads();
    s[t] += v;
    __syncthreads();
  }
  int excl = t ? s[t - 1] : 0;
  bs[t] = excl;
  cur[t] = excl;
  if (t == K - 1) bs[K] = s[K - 1];
}

// ---------------------------------------------------------------------------
// Coarse bin edges: binned[pos] = (local_row<<17) | src.  Block-batched
// cursor reservation -> contiguous write runs. int4 loads.
// ---------------------------------------------------------------------------
__global__ __launch_bounds__(256) void bin_edges(
    const int* __restrict__ dst, const int* __restrict__ src,
    int* __restrict__ cur, int* __restrict__ binned) {
  __shared__ int h[K];
  int t = threadIdx.x;
  if (t < K) h[t] = 0;
  __syncthreads();
  int base = blockIdx.x * CHUNK;
  int end = min(base + CHUNK, Ee);
  for (int i = base + t * 4; i < end; i += 1024) {
    int4 d4 = *(const int4*)(dst + i);
    atomicAdd(&h[d4.x / RPB], 1);
    atomicAdd(&h[d4.y / RPB], 1);
    atomicAdd(&h[d4.z / RPB], 1);
    atomicAdd(&h[d4.w / RPB], 1);
  }
  __syncthreads();
  if (t < K) {
    int c = h[t];
    h[t] = c ? atomicAdd(&cur[t], c) : 0;
  }
  __syncthreads();
  for (int i = base + t * 4; i < end; i += 1024) {
    int4 d4 = *(const int4*)(dst + i);
    int4 s4 = *(const int4*)(src + i);
#define BE_ONE(D, S)                                    \
    {                                                   \
      int k = (D) / RPB;                                \
      int lr = (D) - k * RPB;                           \
      int pos = atomicAdd(&h[k], 1);                    \
      binned[pos] = (lr << 17) | (S);                   \
    }
    BE_ONE(d4.x, s4.x)
    BE_ONE(d4.y, s4.y)
    BE_ONE(d4.z, s4.z)
    BE_ONE(d4.w, s4.w)
#undef BE_ONE
  }
}

// ---------------------------------------------------------------------------
// Coarse bin pm: bp[pos] = { (local_row<<22)|col , bits(val) }. int4 loads.
// ---------------------------------------------------------------------------
__global__ __launch_bounds__(256) void bin_pm(
    const int* __restrict__ rows, const int* __restrict__ cols,
    const float* __restrict__ vals,
    int* __restrict__ cur, int2* __restrict__ bp) {
  __shared__ int h[K];
  int t = threadIdx.x;
  if (t < K) h[t] = 0;
  __syncthreads();
  int base = blockIdx.x * CHUNK;
  int end = min(base + CHUNK, NNZn);
  for (int i = base + t * 4; i < end; i += 1024) {
    int4 r4 = *(const int4*)(rows + i);
    atomicAdd(&h[r4.x / RPB], 1);
    atomicAdd(&h[r4.y / RPB], 1);
    atomicAdd(&h[r4.z / RPB], 1);
    atomicAdd(&h[r4.w / RPB], 1);
  }
  __syncthreads();
  if (t < K) {
    int c = h[t];
    h[t] = c ? atomicAdd(&cur[t], c) : 0;
  }
  __syncthreads();
  for (int i = base + t * 4; i < end; i += 1024) {
    int4 r4 = *(const int4*)(rows + i);
    int4 c4 = *(const int4*)(cols + i);
    float4 v4 = *(const float4*)(vals + i);
#define BP_ONE(R, C, V)                                         \
    {                                                           \
      int k = (R) / RPB;                                        \
      int lr = (R) - k * RPB;                                   \
      int pos = atomicAdd(&h[k], 1);                            \
      bp[pos] = make_int2((lr << 22) | (C), __float_as_int(V)); \
    }
    BP_ONE(r4.x, c4.x, v4.x)
    BP_ONE(r4.y, c4.y, v4.y)
    BP_ONE(r4.z, c4.z, v4.z)
    BP_ONE(r4.w, c4.w, v4.w)
#undef BP_ONE
  }
}

// ---------------------------------------------------------------------------
// Fused pm consume: one block per bucket, LDS float accumulators (stride 17),
// each thread gathers full 64B feat_b rows (4x float4, unroll x2 -> 8 loads
// in flight) and accumulates via LDS atomics. No staging, no sort.
// ---------------------------------------------------------------------------
__global__ __launch_bounds__(1024) void pm_fused(
    const float* __restrict__ fb, const int2* __restrict__ bp,
    const int* __restrict__ bs, float* __restrict__ pmy) {
  __shared__ float acc[RPB * 17];
  int b = blockIdx.x, t = threadIdx.x;
  for (int i = t; i < RPB * 17; i += 1024) acc[i] = 0.f;
  __syncthreads();
  int s0 = bs[b], s1 = bs[b + 1];
  int i = s0 + t;
  for (; i + 1024 < s1; i += 2048) {
    int2 e0 = bp[i];
    int2 e1 = bp[i + 1024];
    const float4* p0 = (const float4*)(fb + (size_t)(e0.x & 0x3FFFFF) * 16);
    const float4* p1 = (const float4*)(fb + (size_t)(e1.x & 0x3FFFFF) * 16);
    float4 a0 = p0[0], b0 = p0[1], c0 = p0[2], d0 = p0[3];
    float4 a1 = p1[0], b1 = p1[1], c1 = p1[2], d1 = p1[3];
    float v0 = __int_as_float(e0.y);
    float v1 = __int_as_float(e1.y);
    float* q0 = &acc[(e0.x >> 22) * 17];
    float* q1 = &acc[(e1.x >> 22) * 17];
    atomicAdd(&q0[0],  v0 * a0.x); atomicAdd(&q0[1],  v0 * a0.y);
    atomicAdd(&q0[2],  v0 * a0.z); atomicAdd(&q0[3],  v0 * a0.w);
    atomicAdd(&q0[4],  v0 * b0.x); atomicAdd(&q0[5],  v0 * b0.y);
    atomicAdd(&q0[6],  v0 * b0.z); atomicAdd(&q0[7],  v0 * b0.w);
    atomicAdd(&q0[8],  v0 * c0.x); atomicAdd(&q0[9],  v0 * c0.y);
    atomicAdd(&q0[10], v0 * c0.z); atomicAdd(&q0[11], v0 * c0.w);
    atomicAdd(&q0[12], v0 * d0.x); atomicAdd(&q0[13], v0 * d0.y);
    atomicAdd(&q0[14], v0 * d0.z); atomicAdd(&q0[15], v0 * d0.w);
    atomicAdd(&q1[0],  v1 * a1.x); atomicAdd(&q1[1],  v1 * a1.y);
    atomicAdd(&q1[2],  v1 * a1.z); atomicAdd(&q1[3],  v1 * a1.w);
    atomicAdd(&q1[4],  v1 * b1.x); atomicAdd(&q1[5],  v1 * b1.y);
    atomicAdd(&q1[6],  v1 * b1.z); atomicAdd(&q1[7],  v1 * b1.w);
    atomicAdd(&q1[8],  v1 * c1.x); atomicAdd(&q1[9],  v1 * c1.y);
    atomicAdd(&q1[10], v1 * c1.z); atomicAdd(&q1[11], v1 * c1.w);
    atomicAdd(&q1[12], v1 * d1.x); atomicAdd(&q1[13], v1 * d1.y);
    atomicAdd(&q1[14], v1 * d1.z); atomicAdd(&q1[15], v1 * d1.w);
  }
  for (; i < s1; i += 1024) {
    int2 e0 = bp[i];
    const float4* p0 = (const float4*)(fb + (size_t)(e0.x & 0x3FFFFF) * 16);
    float4 a0 = p0[0], b0 = p0[1], c0 = p0[2], d0 = p0[3];
    float v0 = __int_as_float(e0.y);
    float* q0 = &acc[(e0.x >> 22) * 17];
    atomicAdd(&q0[0],  v0 * a0.x); atomicAdd(&q0[1],  v0 * a0.y);
    atomicAdd(&q0[2],  v0 * a0.z); atomicAdd(&q0[3],  v0 * a0.w);
    atomicAdd(&q0[4],  v0 * b0.x); atomicAdd(&q0[5],  v0 * b0.y);
    atomicAdd(&q0[6],  v0 * b0.z); atomicAdd(&q0[7],  v0 * b0.w);
    atomicAdd(&q0[8],  v0 * c0.x); atomicAdd(&q0[9],  v0 * c0.y);
    atomicAdd(&q0[10], v0 * c0.z); atomicAdd(&q0[11], v0 * c0.w);
    atomicAdd(&q0[12], v0 * d0.x); atomicAdd(&q0[13], v0 * d0.y);
    atomicAdd(&q0[14], v0 * d0.z); atomicAdd(&q0[15], v0 * d0.w);
  }
  __syncthreads();
  int r0 = b * RPB;
  int nr = min(RPB, Nn - r0);
  for (int j = t; j < nr * 16; j += 1024)
    pmy[(size_t)r0 * 16 + j] = acc[(j >> 4) * 17 + (j & 15)];
}

// ---------------------------------------------------------------------------
// Per-bucket sort (edges): LDS 391-row hist + 512-wide scan, write row_ptr,
// scatter into contiguous CSR run [bs[b], bs[b+1]).
// ---------------------------------------------------------------------------
__global__ __launch_bounds__(1024) void sort_edges(
    const int* __restrict__ be, const int* __restrict__ bs,
    int* __restrict__ csr, int* __restrict__ rp) {
  __shared__ int hist[RPB];
  __shared__ int sc[512];
  int b = blockIdx.x, t = threadIdx.x;
  if (t < RPB) hist[t] = 0;
  __syncthreads();
  int s0 = bs[b], s1 = bs[b + 1];
  for (int i = s0 + t; i < s1; i += 1024)
    atomicAdd(&hist[be[i] >> 17], 1);
  __syncthreads();
  if (t < 512) sc[t] = (t < RPB) ? hist[t] : 0;
  __syncthreads();
  for (int off = 1; off < 512; off <<= 1) {
    int v = 0;
    if (t < 512 && t >= off) v = sc[t - off];
    __syncthreads();
    if (t < 512) sc[t] += v;
    __syncthreads();
  }
  int r0 = b * RPB;
  if (t < RPB) {
    int r = r0 + t;
    if (r < Nn) rp[r + 1] = s0 + sc[t];
    hist[t] = s0 + sc[t] - hist[t];  // exclusive start = cursor
  }
  if (b == 0 && t == 0) rp[0] = 0;
  __syncthreads();
  for (int i = s0 + t; i < s1; i += 1024) {
    int p = be[i];
    int pos = atomicAdd(&hist[p >> 17], 1);
    csr[pos] = p & 0x1FFFF;
  }
}

// ---------------------------------------------------------------------------
// CSR hop, float4: 4 lanes per row, 8 float4 gathers in flight per lane.
// ---------------------------------------------------------------------------
__global__ __launch_bounds__(256) void hop_csr4(
    const float* __restrict__ zin, float* __restrict__ zout,
    const int* __restrict__ cs, const int* __restrict__ rp) {
  int gid = (blockIdx.x * 256 + threadIdx.x) >> 2;
  int q = (threadIdx.x & 3) * 4;
  if (gid >= Nn) return;
  int j = rp[gid], e = rp[gid + 1];
  float ax = 0.f, ay = 0.f, az = 0.f, aw = 0.f;
  for (; j + 8 <= e; j += 8) {
    int s0 = cs[j],     s1 = cs[j + 1], s2 = cs[j + 2], s3 = cs[j + 3];
    int s4 = cs[j + 4], s5 = cs[j + 5], s6 = cs[j + 6], s7 = cs[j + 7];
    float4 x0 = *(const float4*)(zin + (size_t)s0 * 16 + q);
    float4 x1 = *(const float4*)(zin + (size_t)s1 * 16 + q);
    float4 x2 = *(const float4*)(zin + (size_t)s2 * 16 + q);
    float4 x3 = *(const float4*)(zin + (size_t)s3 * 16 + q);
    float4 x4 = *(const float4*)(zin + (size_t)s4 * 16 + q);
    float4 x5 = *(const float4*)(zin + (size_t)s5 * 16 + q);
    float4 x6 = *(const float4*)(zin + (size_t)s6 * 16 + q);
    float4 x7 = *(const float4*)(zin + (size_t)s7 * 16 + q);
    ax += ((x0.x + x1.x) + (x2.x + x3.x)) + ((x4.x + x5.x) + (x6.x + x7.x));
    ay += ((x0.y + x1.y) + (x2.y + x3.y)) + ((x4.y + x5.y) + (x6.y + x7.y));
    az += ((x0.z + x1.z) + (x2.z + x3.z)) + ((x4.z + x5.z) + (x6.z + x7.z));
    aw += ((x0.w + x1.w) + (x2.w + x3.w)) + ((x4.w + x5.w) + (x6.w + x7.w));
  }
  for (; j < e; ++j) {
    float4 x = *(const float4*)(zin + (size_t)cs[j] * 16 + q);
    ax += x.x; ay += x.y; az += x.z; aw += x.w;
  }
  *(float4*)(zout + (size_t)gid * 16 + q) = make_float4(ax, ay, az, aw);
}

// ---------------------------------------------------------------------------
// Fused per-node projections + ReLU(second half) + BN-stat reduction.
// (round-3 verified version: named float4 streaming, no scratch arrays)
// ---------------------------------------------------------------------------
__global__ __launch_bounds__(256) void fuse_kernel(
    const float* __restrict__ feat_a, const float* __restrict__ deg,
    const float* __restrict__ z1, const float* __restrict__ z2,
    const float* __restrict__ z4, const float* __restrict__ pmy,
    const float* __restrict__ Wprev, const float* __restrict__ bprev,
    const float* __restrict__ Wdeg,  const float* __restrict__ bdeg,
    const float* __restrict__ Wrad,  const float* __restrict__ brad,
    const float* __restrict__ Wfuse, const float* __restrict__ bfuse,
    float* __restrict__ result, float* __restrict__ stats) {
  __shared__ float sWp[256], sWd[256], sWr[768], sWf[256], sB[16];
  __shared__ float sstat[32];
  int t = threadIdx.x;
  sWp[t] = Wprev[t];
  sWd[t] = Wdeg[t];
  sWf[t] = Wfuse[t];
  for (int i = t; i < 768; i += 256) sWr[i] = Wrad[i];
  if (t < 32) sstat[t] = 0.f;
  if (t < 16)
    sB[t] = bprev[t] + bdeg[t] + brad[t] + brad[16 + t] + brad[32 + t] + bfuse[t];
  __syncthreads();

  int n = blockIdx.x * 256 + t;
  bool valid = n < Nn;
  int nc = valid ? n : (Nn - 1);   // clamp: loads always in-bounds

  float dg = deg[nc];
  float out[16];
#pragma unroll
  for (int o = 0; o < 16; ++o) out[o] = sB[o];

  const float4* pa = (const float4*)(feat_a + (size_t)nc * 16);
  const float4* p1 = (const float4*)(z1 + (size_t)nc * 16);
  const float4* p2 = (const float4*)(z2 + (size_t)nc * 16);
  const float4* p4 = (const float4*)(z4 + (size_t)nc * 16);
  const float4* pp = (const float4*)(pmy + (size_t)nc * 16);

#define FUSE_STEP(E, XA, X1, X2, X4, XP)                                  \
  {                                                                       \
    int i = c * 4 + (E);                                                  \
    float va = (XA);                                                      \
    float vd = dg * va;                                                   \
    float v1 = (X1), v2 = (X2), v4 = (X4), vp = (XP);                     \
    _Pragma("unroll")                                                     \
    for (int o = 0; o < 16; ++o) {                                        \
      float acc = out[o];                                                 \
      acc = fmaf(va, sWp[i * 16 + o], acc);                               \
      acc = fmaf(vd, sWd[i * 16 + o], acc);                               \
      acc = fmaf(v1, sWr[i * 16 + o], acc);                               \
      acc = fmaf(v2, sWr[256 + i * 16 + o], acc);                         \
      acc = fmaf(v4, sWr[512 + i * 16 + o], acc);                         \
      acc = fmaf(vp, sWf[i * 16 + o], acc);                               \
      out[o] = acc;                                                       \
    }                                                                     \
  }

#pragma unroll
  for (int c = 0; c < 4; ++c) {
    float4 xa = pa[c];
    float4 x1 = p1[c];
    float4 x2 = p2[c];
    float4 x4 = p4[c];
    float4 xp = pp[c];
    FUSE_STEP(0, xa.x, x1.x, x2.x, x4.x, xp.x)
    FUSE_STEP(1, xa.y, x1.y, x2.y, x4.y, xp.y)
    FUSE_STEP(2, xa.z, x1.z, x2.z, x4.z, xp.z)
    FUSE_STEP(3, xa.w, x1.w, x2.w, x4.w, xp.w)
  }
#undef FUSE_STEP

#pragma unroll
  for (int o = 8; o < 16; ++o) out[o] = fmaxf(out[o], 0.f);

  if (valid) {
    float4* r = (float4*)(result + (size_t)n * 16);
    r[0] = make_float4(out[0], out[1], out[2], out[3]);
    r[1] = make_float4(out[4], out[5], out[6], out[7]);
    r[2] = make_float4(out[8], out[9], out[10], out[11]);
    r[3] = make_float4(out[12], out[13], out[14], out[15]);
  } else {
#pragma unroll
    for (int o = 0; o < 16; ++o) out[o] = 0.f;
  }

#pragma unroll
  for (int o = 0; o < 16; ++o) {
    float s = out[o];
    float qq = out[o] * out[o];
#pragma unroll
    for (int m = 32; m >= 1; m >>= 1) {
      s += __shfl_xor(s, m, 64);
      qq += __shfl_xor(qq, m, 64);
    }
    if ((t & 63) == 0) {
      atomicAdd(&sstat[o], s);
      atomicAdd(&sstat[16 + o], qq);
    }
  }
  __syncthreads();
  if (t < 32) atomicAdd(&stats[t], sstat[t]);
}

// ---------------------------------------------------------------------------
__global__ void bn_coeffs(float* __restrict__ stats,
                          const float* __restrict__ gamma,
                          const float* __restrict__ beta) {
  int t = threadIdx.x;
  if (t < 16) {
    float mean = stats[t] * (1.0f / Nn);
    float var  = stats[16 + t] * (1.0f / Nn) - mean * mean;
    float sc   = gamma[t] * rsqrtf(var + 1e-5f);
    stats[32 + t] = sc;
    stats[48 + t] = beta[t] - mean * sc;
  }
}

__global__ __launch_bounds__(256) void bn_apply(
    float* __restrict__ result, const float* __restrict__ stats) {
  int idx = blockIdx.x * 256 + threadIdx.x;          // over Nn*4
  if (idx >= Nn * 4) return;
  int c = (idx & 3) * 4;
  float4 r = ((const float4*)result)[idx];
  float4 o;
  o.x = r.x * stats[32 + c + 0] + stats[48 + c + 0];
  o.y = r.y * stats[32 + c + 1] + stats[48 + c + 1];
  o.z = r.z * stats[32 + c + 2] + stats[48 + c + 2];
  o.w = r.w * stats[32 + c + 3] + stats[48 + c + 3];
  ((float4*)result)[idx] = o;
}

// ---------------------------------------------------------------------------
extern "C" void kernel_launch(void* const* d_in, const int* in_sizes, int n_in,
                              void* d_out, int out_size, void* d_ws, size_t ws_size,
                              hipStream_t stream) {
  const float* feat_a  = (const float*)d_in[0];
  const float* feat_b  = (const float*)d_in[1];
  const float* deg     = (const float*)d_in[2];
  const float* pm_vals = (const float*)d_in[3];
  const float* W_prev  = (const float*)d_in[4];
  const float* b_prev  = (const float*)d_in[5];
  const float* W_deg   = (const float*)d_in[6];
  const float* b_deg   = (const float*)d_in[7];
  const float* W_rad   = (const float*)d_in[8];
  const float* b_rad   = (const float*)d_in[9];
  const float* W_fuse  = (const float*)d_in[10];
  const float* b_fuse  = (const float*)d_in[11];
  const float* bn_g    = (const float*)d_in[12];
  const float* bn_b    = (const float*)d_in[13];
  const int*   src     = (const int*)d_in[14];
  const int*   dst     = (const int*)d_in[15];
  const int*   pm_rows = (const int*)d_in[16];
  const int*   pm_cols = (const int*)d_in[17];

  int* ws = (int*)d_ws;
  // Region A (Ee ints = 12.8MB): edge CSR (csr_src).
  // Region B (2*NNZ ints = 51.2MB): binned pm, then binned edges, then z1..z4.
  int*   A    = ws;
  int*   B    = ws + (size_t)Ee;
  float* pm_y = (float*)(ws + (size_t)Ee + 2 * (size_t)NNZn);   // NF floats
  int*   T    = (int*)(pm_y + NF);
  int*   tot_e = T;                       // K
  int*   tot_p = T + K;                   // K
  float* stats = (float*)(T + 2 * K);     // 64
  int*   bs_e  = T + 2 * K + 64;          // K+1
  int*   cur_e = bs_e + K + 1;            // K
  int*   bs_p  = cur_e + K;               // K+1
  int*   cur_p = bs_p + K + 1;            // K
  int*   rp_e  = cur_p + K;               // Nn+1

  int2*  bp       = (int2*)B;
  int*   binned_e = B;
  int*   csr_src  = A;
  float* z1 = (float*)B;
  float* z2 = z1 + (size_t)NF;
  float* z3 = z2 + (size_t)NF;
  float* z4 = z3 + (size_t)NF;
  float* result = (float*)d_out;

  // zero coarse totals + stats (contiguous)
  hipMemsetAsync(T, 0, (size_t)(2 * K + 64) * sizeof(int), stream);

  int cb_e = (Ee + CHUNK - 1) / CHUNK;     // 196
  int cb_p = (NNZn + CHUNK - 1) / CHUNK;   // 391
  count_kernel<<<cb_e, 256, 0, stream>>>(dst, Ee, tot_e);
  count_kernel<<<cb_p, 256, 0, stream>>>(pm_rows, NNZn, tot_p);
  scan_kernel<<<2, K, 0, stream>>>(tot_e, tot_p, bs_e, cur_e, bs_p, cur_p);

  // pm: coarse bin -> single fused LDS-accumulate consume
  bin_pm<<<cb_p, 256, 0, stream>>>(pm_rows, pm_cols, pm_vals, cur_p, bp);
  pm_fused<<<K, 1024, 0, stream>>>(feat_b, bp, bs_p, pm_y);

  // edges: coarse bin into B[0..Ee) (bp dead), sort into A
  bin_edges<<<cb_e, 256, 0, stream>>>(dst, src, cur_e, binned_e);
  sort_edges<<<K, 1024, 0, stream>>>(binned_e, bs_e, csr_src, rp_e);

  // hops (z buffers overwrite binned_e region, dead after sort_edges)
  int hop_blocks = (Nn * 4 + 255) / 256;   // 1563
  hop_csr4<<<hop_blocks, 256, 0, stream>>>(feat_a, z1, csr_src, rp_e);
  hop_csr4<<<hop_blocks, 256, 0, stream>>>(z1, z2, csr_src, rp_e);
  hop_csr4<<<hop_blocks, 256, 0, stream>>>(z2, z3, csr_src, rp_e);
  hop_csr4<<<hop_blocks, 256, 0, stream>>>(z3, z4, csr_src, rp_e);

  int fuse_blocks = (Nn + 255) / 256;
  fuse_kernel<<<fuse_blocks, 256, 0, stream>>>(
      feat_a, deg, z1, z2, z4, pm_y,
      W_prev, b_prev, W_deg, b_deg, W_rad, b_rad, W_fuse, b_fuse,
      result, stats);

  bn_coeffs<<<1, 64, 0, stream>>>(stats, bn_g, bn_b);

  int bn_blocks = (Nn * 4 + 255) / 256;
  bn_apply<<<bn_blocks, 256, 0, stream>>>(result, stats);
}